// Round 8
// baseline (824.698 us; speedup 1.0000x reference)
//
#include <hip/hip_runtime.h>
#include <hip/hip_bf16.h>
#include <math.h>

#define DIMC 256
#define INNERC 128
#define HEADSC 4
#define DHC 32
#define QKVC 384

typedef __attribute__((ext_vector_type(8))) short bf16frag;   // 8 bf16 = 4 VGPRs
typedef __attribute__((ext_vector_type(4))) float f32x4;

__device__ __forceinline__ float gelu_exact(float x) {
    return 0.5f * x * (1.0f + erff(x * 0.70710678118654752f));
}

__device__ __forceinline__ float b2f(short s) {
    return __uint_as_float(((unsigned)(unsigned short)s) << 16);
}

__device__ __forceinline__ void gload_lds16(const void* g, void* l) {
    __builtin_amdgcn_global_load_lds(
        (const __attribute__((address_space(1))) void*)g,
        (__attribute__((address_space(3))) void*)l, 16, 0, 0);
}

// ---------------- LayerNorm: fp32 in, bf16 out ----------------
__global__ __launch_bounds__(256)
void ln_kernel(const float* __restrict__ x, const float* __restrict__ g,
               const float* __restrict__ b, __hip_bfloat16* __restrict__ out)
{
    int i = blockIdx.x;
    int t = threadIdx.x;
    float v = x[(size_t)i * DIMC + t];
    __shared__ float red[4];
    float s = v;
#pragma unroll
    for (int off = 32; off; off >>= 1) s += __shfl_xor(s, off);
    if ((t & 63) == 0) red[t >> 6] = s;
    __syncthreads();
    float mean = (red[0] + red[1] + red[2] + red[3]) * (1.f / DIMC);
    float c = v - mean;
    float s2 = c * c;
#pragma unroll
    for (int off = 32; off; off >>= 1) s2 += __shfl_xor(s2, off);
    __syncthreads();
    if ((t & 63) == 0) red[t >> 6] = s2;
    __syncthreads();
    float var = (red[0] + red[1] + red[2] + red[3]) * (1.f / DIMC);
    out[(size_t)i * DIMC + t] =
        __float2bfloat16(c * rsqrtf(var + 1e-5f) * g[t] + b[t]);
}

// ---------------- fp32 -> bf16 convert (n % 4 == 0) ----------------
__global__ void f2b_kernel(const float* __restrict__ src,
                           __hip_bfloat16* __restrict__ dst, int n)
{
    int i = (blockIdx.x * blockDim.x + threadIdx.x) * 4;
    if (i < n) {
        float4 v = *(const float4*)(src + i);
        dst[i + 0] = __float2bfloat16(v.x);
        dst[i + 1] = __float2bfloat16(v.y);
        dst[i + 2] = __float2bfloat16(v.z);
        dst[i + 3] = __float2bfloat16(v.w);
    }
}

// ---------------- pack wq/wk/wv -> wqkv bf16 [4][384][256], biases [4][384] ----
__global__ __launch_bounds__(256)
void packqkv_kernel(const float* __restrict__ wq, const float* __restrict__ wk,
                    const float* __restrict__ wv, const float* __restrict__ bq,
                    const float* __restrict__ bk, const float* __restrict__ bv,
                    __hip_bfloat16* __restrict__ wqkv, float* __restrict__ bqkv)
{
    int row = blockIdx.x;                 // 0 .. 4*384-1
    int l = row / QKVC, c = row % QKVC;
    int which = c >> 7, cc = c & 127;
    const float* srcw = which == 0 ? wq : which == 1 ? wk : wv;
    const float* srcb = which == 0 ? bq : which == 1 ? bk : bv;
    srcw += ((size_t)l * INNERC + cc) * DIMC;
    wqkv[(size_t)row * DIMC + threadIdx.x] = __float2bfloat16(srcw[threadIdx.x]);
    if (threadIdx.x == 0) bqkv[row] = srcb[l * INNERC + cc];
}

// ---------------- MFMA GEMM: single-buffered (R5-proven), XCD-chunked grid --
// C[M][OUT] = A[M][K] @ W[OUT][K]^T + bias.  BM=128, BK=64, BN in {64,128}.
// EPI: 0 = bias -> bf16; 1 = bias+gelu -> bf16; 2 = bias+res -> fp32.
template<int EPI, int BN>
__global__ __launch_bounds__(256)
void mfma_gemm(const __hip_bfloat16* __restrict__ A,
               const __hip_bfloat16* __restrict__ W,
               const float* __restrict__ bias, const float* __restrict__ res,
               void* __restrict__ Cout, int M, int K, int OUT,
               int mtiles, int ntiles)
{
    constexpr int NFR = BN / 32;
    constexpr int ASZ = 128 * 128;          // A tile bytes (128 rows x 128B)
    __shared__ char lds[ASZ + BN * 128];

    int nwg = mtiles * ntiles;
    int orig = blockIdx.x;
    int q = nwg >> 3, r = nwg & 7;
    int xcd = orig & 7, loc = orig >> 3;
    int wgid = (xcd < r ? xcd * (q + 1) : r * (q + 1) + (xcd - r) * q) + loc;
    int bm = (wgid / ntiles) * 128;
    int bn = (wgid % ntiles) * BN;

    int tid = threadIdx.x;
    int lane = tid & 63;
    int w = tid >> 6;
    int wr = w >> 1, wc = w & 1;

    f32x4 acc[4][NFR] = {};

    for (int k0 = 0; k0 < K; k0 += 64) {
#pragma unroll
        for (int it = 0; it < 4; ++it) {             // A: 1024 chunks
            int chunk = it * 256 + tid;
            int rr = chunk >> 3;
            int sc = (chunk & 7) ^ (rr & 7);
            int grow = bm + rr;
            if (grow < M)
                gload_lds16((const char*)A + ((size_t)grow * K + k0) * 2 + sc * 16,
                            lds + chunk * 16);
        }
#pragma unroll
        for (int it = 0; it < BN / 32; ++it) {       // W: BN*8 chunks
            int chunk = it * 256 + tid;
            int rr = chunk >> 3;
            int sc = (chunk & 7) ^ (rr & 7);
            gload_lds16((const char*)W + ((size_t)(bn + rr) * K + k0) * 2 + sc * 16,
                        lds + ASZ + chunk * 16);
        }
        __syncthreads();

#pragma unroll
        for (int s = 0; s < 2; ++s) {
            bf16frag af[4], bfr[NFR];
            int kb = s * 64 + ((lane >> 4) << 4);
#pragma unroll
            for (int m = 0; m < 4; ++m) {
                int ar = wr * 64 + m * 16 + (lane & 15);
                af[m] = *(const bf16frag*)(lds + ar * 128 + (kb ^ ((ar & 7) << 4)));
            }
#pragma unroll
            for (int n = 0; n < NFR; ++n) {
                int br = wc * (BN / 2) + n * 16 + (lane & 15);
                bfr[n] = *(const bf16frag*)(lds + ASZ + br * 128 + (kb ^ ((br & 7) << 4)));
            }
#pragma unroll
            for (int m = 0; m < 4; ++m)
#pragma unroll
                for (int n = 0; n < NFR; ++n)
                    acc[m][n] = __builtin_amdgcn_mfma_f32_16x16x32_bf16(
                        af[m], bfr[n], acc[m][n], 0, 0, 0);
        }
        __syncthreads();
    }

#pragma unroll
    for (int m = 0; m < 4; ++m)
#pragma unroll
        for (int rr = 0; rr < 4; ++rr) {
            int grow = bm + wr * 64 + m * 16 + ((lane >> 4) << 2) + rr;
            if (grow < M) {
#pragma unroll
                for (int n = 0; n < NFR; ++n) {
                    int gcol = bn + wc * (BN / 2) + n * 16 + (lane & 15);
                    float val = acc[m][n][rr] + bias[gcol];
                    if (EPI == 1) val = gelu_exact(val);
                    if (EPI == 2) {
                        val += res[(size_t)grow * OUT + gcol];
                        ((float*)Cout)[(size_t)grow * OUT + gcol] = val;
                    } else {
                        ((__hip_bfloat16*)Cout)[(size_t)grow * OUT + gcol] =
                            __float2bfloat16(val);
                    }
                }
            }
        }
}

// ---------------- Fused FFN: x_out = x + FF2(gelu(FF1(h))) -------------------
// h bf16 [M][256]; W1 [1024][256]; W2 [256][1024]; res/out fp32 [M][256].
// BM=64 per block, 256 thr (2x2 waves, wave tile 32 x 64 per GEMM half).
// LDS 80KB: hS 32K (64x512B) | uS 16K (64x256B) | wS 32K (128x256B, reused 4x/iter).
// u never touches HBM. XOR swizzle: 16B-chunk index ^ (row&15).
__global__ __launch_bounds__(256)
void fused_ff(const __hip_bfloat16* __restrict__ h,
              const __hip_bfloat16* __restrict__ W1,
              const float* __restrict__ b1,
              const __hip_bfloat16* __restrict__ W2,
              const float* __restrict__ b2,
              const float* __restrict__ res,
              float* __restrict__ out, int M, int mtiles)
{
    __shared__ char lds[81920];
    constexpr int US = 32768, WS = 49152;

    int tid = threadIdx.x;
    int lane = tid & 63;
    int w = tid >> 6, wr = w >> 1, wc = w & 1;
    int l15 = lane & 15, l4 = lane >> 4;

    // bijective XCD chunk swizzle over M-tiles
    int orig = blockIdx.x;
    int q = mtiles >> 3, r8 = mtiles & 7;
    int xcd = orig & 7, loc = orig >> 3;
    int wgid = (xcd < r8 ? xcd * (q + 1) : r8 * (q + 1) + (xcd - r8) * q) + loc;
    int bm = wgid * 64;

    // ---- stage h tile: 64 rows x 512B = 2048 chunks ----
#pragma unroll
    for (int it = 0; it < 8; ++it) {
        int c = it * 256 + tid;
        int row = c >> 5, cc = c & 31;
        int sc = cc ^ (row & 15);
        if (bm + row < M)
            gload_lds16((const char*)h + ((size_t)(bm + row) * 256) * 2 + sc * 16,
                        lds + c * 16);
    }
    __syncthreads();

    f32x4 accC[2][2][4] = {};   // [oh][mf][nf]

    for (int i = 0; i < 8; ++i) {           // n1-blocks of 128
        f32x4 accU[2][4] = {};              // [mf][nf]

        // ---- FF1: u-blk = h @ W1_blk^T, K=256 in 2 halves ----
#pragma unroll
        for (int kh = 0; kh < 2; ++kh) {
#pragma unroll
            for (int it = 0; it < 8; ++it) {       // W1 half: 128x256B
                int c = it * 256 + tid;
                int row = c >> 4, cc = c & 15;
                int sc = cc ^ (row & 15);
                gload_lds16((const char*)W1 + ((size_t)(i * 128 + row) * 256 + kh * 128) * 2 + sc * 16,
                            lds + WS + c * 16);
            }
            __syncthreads();                        // W1 half ready
#pragma unroll
            for (int s = 0; s < 4; ++s) {
                int kbh = kh * 256 + s * 64 + l4 * 16;   // byte in 512B h-row
                int chA = kbh >> 4;
                int kbl = s * 64 + l4 * 16;
                int chW = kbl >> 4;
                bf16frag af[2], bfr[4];
#pragma unroll
                for (int mf = 0; mf < 2; ++mf) {
                    int ar = wr * 32 + mf * 16 + l15;
                    af[mf] = *(const bf16frag*)(lds + ar * 512 + ((chA ^ (ar & 15)) << 4));
                }
#pragma unroll
                for (int nf = 0; nf < 4; ++nf) {
                    int br = wc * 64 + nf * 16 + l15;
                    bfr[nf] = *(const bf16frag*)(lds + WS + br * 256 + ((chW ^ (br & 15)) << 4));
                }
#pragma unroll
                for (int mf = 0; mf < 2; ++mf)
#pragma unroll
                    for (int nf = 0; nf < 4; ++nf)
                        accU[mf][nf] = __builtin_amdgcn_mfma_f32_16x16x32_bf16(
                            af[mf], bfr[nf], accU[mf][nf], 0, 0, 0);
            }
            __syncthreads();                        // wS reads done (WAR)
        }

        // ---- stage W2 oh=0 early (flies during gelu + u writes) ----
#pragma unroll
        for (int it = 0; it < 8; ++it) {
            int c = it * 256 + tid;
            int row = c >> 4, cc = c & 15;
            int sc = cc ^ (row & 15);
            gload_lds16((const char*)W2 + ((size_t)row * 1024 + i * 128) * 2 + sc * 16,
                        lds + WS + c * 16);
        }

        // ---- bias + gelu -> bf16 -> uS (swizzled) ----
        __hip_bfloat16* uSp = (__hip_bfloat16*)(lds + US);
#pragma unroll
        for (int mf = 0; mf < 2; ++mf)
#pragma unroll
            for (int nf = 0; nf < 4; ++nf) {
                int col = wc * 64 + nf * 16 + l15;
                float bb = b1[i * 128 + col];
#pragma unroll
                for (int r = 0; r < 4; ++r) {
                    float v = gelu_exact(accU[mf][nf][r] + bb);
                    int m = wr * 32 + mf * 16 + l4 * 4 + r;
                    int eo = m * 128 + (((col >> 3) ^ (m & 15)) << 3) + (col & 7);
                    uSp[eo] = __float2bfloat16(v);
                }
            }
        __syncthreads();                            // uS + W2 oh0 ready

        // ---- FF2: C += u_blk @ W2_blk^T, two o-halves ----
#pragma unroll
        for (int oh = 0; oh < 2; ++oh) {
            if (oh == 1) {
#pragma unroll
                for (int it = 0; it < 8; ++it) {
                    int c = it * 256 + tid;
                    int row = c >> 4, cc = c & 15;
                    int sc = cc ^ (row & 15);
                    gload_lds16((const char*)W2 + ((size_t)(128 + row) * 1024 + i * 128) * 2 + sc * 16,
                                lds + WS + c * 16);
                }
                __syncthreads();                    // W2 oh1 ready
            }
#pragma unroll
            for (int s = 0; s < 4; ++s) {
                int kbl = s * 64 + l4 * 16;
                int ch = kbl >> 4;
                bf16frag af[2], bfr[4];
#pragma unroll
                for (int mf = 0; mf < 2; ++mf) {
                    int ar = wr * 32 + mf * 16 + l15;
                    af[mf] = *(const bf16frag*)(lds + US + ar * 256 + ((ch ^ (ar & 15)) << 4));
                }
#pragma unroll
                for (int nf = 0; nf < 4; ++nf) {
                    int br = wc * 64 + nf * 16 + l15;
                    bfr[nf] = *(const bf16frag*)(lds + WS + br * 256 + ((ch ^ (br & 15)) << 4));
                }
#pragma unroll
                for (int mf = 0; mf < 2; ++mf)
#pragma unroll
                    for (int nf = 0; nf < 4; ++nf)
                        accC[oh][mf][nf] = __builtin_amdgcn_mfma_f32_16x16x32_bf16(
                            af[mf], bfr[nf], accC[oh][mf][nf], 0, 0, 0);
            }
            __syncthreads();        // oh0: wS reads done (WAR for oh1 stage)
        }                           // oh1: wS+uS reads done (WAR for next iter)
    }

    // ---- epilogue: + b2 + res -> fp32 out ----
#pragma unroll
    for (int oh = 0; oh < 2; ++oh)
#pragma unroll
        for (int mf = 0; mf < 2; ++mf)
#pragma unroll
            for (int r = 0; r < 4; ++r) {
                int m = bm + wr * 32 + mf * 16 + l4 * 4 + r;
                if (m < M) {
#pragma unroll
                    for (int nf = 0; nf < 4; ++nf) {
                        int o = oh * 128 + wc * 64 + nf * 16 + l15;
                        float val = accC[oh][mf][nf][r] + b2[o] + res[(size_t)m * 256 + o];
                        out[(size_t)m * 256 + o] = val;
                    }
                }
            }
}

// ---------------- CSR build ----------------
__global__ void count_kernel(const int* __restrict__ dst, int* __restrict__ count, int E)
{
    int e = blockIdx.x * blockDim.x + threadIdx.x;
    if (e < E) atomicAdd(&count[dst[e]], 1);
}

__global__ __launch_bounds__(1024)
void scan_kernel(const int* __restrict__ count, int* __restrict__ rowptr, int N)
{
    __shared__ int sdata[1024];
    __shared__ int carry_s;
    int t = threadIdx.x;
    if (t == 0) { carry_s = 0; rowptr[0] = 0; }
    __syncthreads();
    for (int base = 0; base < N; base += 1024) {
        int idx = base + t;
        int v = (idx < N) ? count[idx] : 0;
        sdata[t] = v;
        __syncthreads();
        for (int off = 1; off < 1024; off <<= 1) {
            int add = (t >= off) ? sdata[t - off] : 0;
            __syncthreads();
            sdata[t] += add;
            __syncthreads();
        }
        if (idx < N) rowptr[idx + 1] = carry_s + sdata[t];
        __syncthreads();
        if (t == 0) carry_s += sdata[1023];
        __syncthreads();
    }
}

__global__ void scatter_kernel(const int* __restrict__ src, const int* __restrict__ dst,
                               const int* __restrict__ rowptr, int* __restrict__ cursor,
                               int* __restrict__ srcperm, int E)
{
    int e = blockIdx.x * blockDim.x + threadIdx.x;
    if (e < E) {
        int d = dst[e];
        int pos = rowptr[d] + atomicAdd(&cursor[d], 1);
        srcperm[pos] = src[e];
    }
}

// ---------------- Attention: one WAVE per node, ILP-restructured ------------
__global__ __launch_bounds__(256)
void attn_kernel(const __hip_bfloat16* __restrict__ qkv, const int* __restrict__ rowptr,
                 const int* __restrict__ srcperm, __hip_bfloat16* __restrict__ agg,
                 int N)
{
    int wid = (blockIdx.x * 256 + threadIdx.x) >> 6;   // node index
    if (wid >= N) return;
    int lane = threadIdx.x & 63;
    int h = lane >> 4, u = lane & 15;
    int i = wid;
    int beg = rowptr[i], deg = rowptr[i + 1] - beg;
    const short* base = (const short*)qkv;
    const float scale = 0.17677669529663687f; // 1/sqrt(32)

    bf16frag qf[4];
    const short* qr = base + (size_t)i * QKVC + h * 32;
#pragma unroll
    for (int c = 0; c < 4; ++c) qf[c] = *(const bf16frag*)(qr + c * 8);

    float m_run = -3.4e38f, d_run = 0.f;
    float accx = 0.f, accy = 0.f;

    int j = (u < deg) ? srcperm[beg + u] : i;

    for (int c0 = 0; c0 < deg; c0 += 16) {
        int cn = min(16, deg - c0);
        bool valid = (u < cn);

        const short* kr = base + (size_t)j * QKVC + 128 + h * 32;
        bf16frag kf[4];
#pragma unroll
        for (int c = 0; c < 4; ++c) kf[c] = *(const bf16frag*)(kr + c * 8);

        int nxt = c0 + 16 + u;
        int jn = (nxt < deg) ? srcperm[beg + nxt] : i;

        float dot = 0.f;
#pragma unroll
        for (int c = 0; c < 4; ++c)
#pragma unroll
            for (int e = 0; e < 8; ++e)
                dot += b2f(qf[c][e]) * b2f(kf[c][e]);
        float alpha = valid ? dot * scale : -3.4e38f;

        float cm = alpha;
#pragma unroll
        for (int off = 8; off; off >>= 1) cm = fmaxf(cm, __shfl_xor(cm, off));
        float m_new = fmaxf(m_run, cm);
        float rescale = expf(m_run - m_new);
        float w = valid ? expf(alpha - m_new) : 0.f;
        float dsum = w;
#pragma unroll
        for (int off = 8; off; off >>= 1) dsum += __shfl_xor(dsum, off);
        d_run = d_run * rescale + dsum;
        m_run = m_new;
        accx *= rescale;
        accy *= rescale;

        float wes[16];
        unsigned vws[16];
#pragma unroll
        for (int e = 0; e < 16; ++e) {
            wes[e] = __shfl(w, h * 16 + e);
            int je = __shfl(j, h * 16 + e);        // invalid slots -> row i
            vws[e] = *(const unsigned*)(base + (size_t)je * QKVC + 256 + h * 32 + u * 2);
        }
#pragma unroll
        for (int e = 0; e < 16; ++e) {
            accx += wes[e] * b2f((short)(vws[e] & 0xffff));
            accy += wes[e] * b2f((short)(vws[e] >> 16));
        }
        j = jn;
    }

    float inv = 1.f / (d_run + 1e-16f);
    __hip_bfloat16* outp = agg + (size_t)i * INNERC + h * 32 + u * 2;
    outp[0] = __float2bfloat16(accx * inv);
    outp[1] = __float2bfloat16(accy * inv);
}

// ---------------- Launch ----------------
extern "C" void kernel_launch(void* const* d_in, const int* in_sizes, int n_in,
                              void* d_out, int out_size, void* d_ws, size_t ws_size,
                              hipStream_t stream)
{
    const float* x    = (const float*)d_in[0];
    const int*   ei   = (const int*)  d_in[1];
    const float* ln1g = (const float*)d_in[2];
    const float* ln1b = (const float*)d_in[3];
    const float* wq   = (const float*)d_in[4];
    const float* bq   = (const float*)d_in[5];
    const float* wk   = (const float*)d_in[6];
    const float* bk   = (const float*)d_in[7];
    const float* wv   = (const float*)d_in[8];
    const float* bv   = (const float*)d_in[9];
    const float* wo   = (const float*)d_in[10];
    const float* bo   = (const float*)d_in[11];
    const float* ln2g = (const float*)d_in[12];
    const float* ln2b = (const float*)d_in[13];
    const float* w1   = (const float*)d_in[14];
    const float* b1   = (const float*)d_in[15];
    const float* w2   = (const float*)d_in[16];
    const float* b2   = (const float*)d_in[17];

    const int N = in_sizes[0] / DIMC;   // 20000
    const int E = in_sizes[1] / 2;      // 320000
    const int* srcIdx = ei;
    const int* dstIdx = ei + E;

    char* p = (char*)d_ws;
    auto alloc = [&](size_t bytes) {
        char* r = p;
        p += (bytes + 255) & ~(size_t)255;
        return r;
    };
    float*          xbuf   = (float*)alloc((size_t)N * DIMC * 4);
    __hip_bfloat16* h      = (__hip_bfloat16*)alloc((size_t)N * DIMC * 2);
    __hip_bfloat16* qkv    = (__hip_bfloat16*)alloc((size_t)N * QKVC * 2);
    __hip_bfloat16* agg    = (__hip_bfloat16*)alloc((size_t)N * INNERC * 2);
    int*            rowptr = (int*)alloc((size_t)(N + 1) * 4);
    int*            cnt    = (int*)alloc((size_t)N * 4);
    int*            srcperm= (int*)alloc((size_t)E * 4);
    __hip_bfloat16* wqkvB  = (__hip_bfloat16*)alloc((size_t)4 * QKVC * DIMC * 2);
    float*          bqkvF  = (float*)alloc((size_t)4 * QKVC * 4);
    __hip_bfloat16* woB    = (__hip_bfloat16*)alloc((size_t)4 * DIMC * INNERC * 2);
    __hip_bfloat16* w1B    = (__hip_bfloat16*)alloc((size_t)4 * 1024 * DIMC * 2);
    __hip_bfloat16* w2B    = (__hip_bfloat16*)alloc((size_t)4 * DIMC * 1024 * 2);

    // Weight conversion (per-call, deterministic)
    packqkv_kernel<<<4 * QKVC, 256, 0, stream>>>(wq, wk, wv, bq, bk, bv, wqkvB, bqkvF);
    {
        int n = 4 * DIMC * INNERC;
        f2b_kernel<<<(n / 4 + 255) / 256, 256, 0, stream>>>(wo, woB, n);
        n = 4 * 1024 * DIMC;
        f2b_kernel<<<(n / 4 + 255) / 256, 256, 0, stream>>>(w1, w1B, n);
        f2b_kernel<<<(n / 4 + 255) / 256, 256, 0, stream>>>(w2, w2B, n);
    }

    // CSR build
    hipMemsetAsync(cnt, 0, (size_t)N * 4, stream);
    count_kernel<<<(E + 255) / 256, 256, 0, stream>>>(dstIdx, cnt, E);
    scan_kernel<<<1, 1024, 0, stream>>>(cnt, rowptr, N);
    hipMemsetAsync(cnt, 0, (size_t)N * 4, stream);
    scatter_kernel<<<(E + 255) / 256, 256, 0, stream>>>(srcIdx, dstIdx, rowptr, cnt, srcperm, E);

    int mt = (N + 127) / 128;        // 157
    int ffmt = (N + 63) / 64;        // 313
    int attnBlocks = (N * 64 + 255) / 256;
    for (int l = 0; l < 4; ++l) {
        const float* xin = (l == 0) ? x : xbuf;
        ln_kernel<<<N, 256, 0, stream>>>(xin, ln1g + l * DIMC, ln1b + l * DIMC, h);
        mfma_gemm<0, 128><<<mt * 3, 256, 0, stream>>>(
            h, wqkvB + (size_t)l * QKVC * DIMC, bqkvF + l * QKVC, nullptr,
            qkv, N, DIMC, QKVC, mt, 3);
        attn_kernel<<<attnBlocks, 256, 0, stream>>>(qkv, rowptr, srcperm, agg, N);
        mfma_gemm<2, 64><<<mt * 4, 256, 0, stream>>>(
            agg, woB + (size_t)l * DIMC * INNERC, bo + l * DIMC, xin,
            xbuf, N, INNERC, DIMC, mt, 4);
        ln_kernel<<<N, 256, 0, stream>>>(xbuf, ln2g + l * DIMC, ln2b + l * DIMC, h);
        float* xout = (l == 3) ? (float*)d_out : xbuf;
        fused_ff<<<ffmt, 256, 0, stream>>>(
            h, w1B + (size_t)l * 1024 * DIMC, b1 + l * 1024,
            w2B + (size_t)l * DIMC * 1024, b2 + l * DIMC,
            xbuf, xout, N, ffmt);
    }
}

// Round 9
// 701.190 us; speedup vs baseline: 1.1761x; 1.1761x over previous
//
#include <hip/hip_runtime.h>
#include <hip/hip_bf16.h>
#include <math.h>

#define DIMC 256
#define INNERC 128
#define HEADSC 4
#define DHC 32
#define QKVC 384

typedef __attribute__((ext_vector_type(8))) short bf16frag;   // 8 bf16 = 4 VGPRs
typedef __attribute__((ext_vector_type(4))) float f32x4;

__device__ __forceinline__ float gelu_exact(float x) {
    return 0.5f * x * (1.0f + erff(x * 0.70710678118654752f));
}

__device__ __forceinline__ float b2f(short s) {
    return __uint_as_float(((unsigned)(unsigned short)s) << 16);
}

__device__ __forceinline__ void gload_lds16(const void* g, void* l) {
    __builtin_amdgcn_global_load_lds(
        (const __attribute__((address_space(1))) void*)g,
        (__attribute__((address_space(3))) void*)l, 16, 0, 0);
}

// ---------------- LayerNorm: fp32 in, bf16 out ----------------
__global__ __launch_bounds__(256)
void ln_kernel(const float* __restrict__ x, const float* __restrict__ g,
               const float* __restrict__ b, __hip_bfloat16* __restrict__ out)
{
    int i = blockIdx.x;
    int t = threadIdx.x;
    float v = x[(size_t)i * DIMC + t];
    __shared__ float red[4];
    float s = v;
#pragma unroll
    for (int off = 32; off; off >>= 1) s += __shfl_xor(s, off);
    if ((t & 63) == 0) red[t >> 6] = s;
    __syncthreads();
    float mean = (red[0] + red[1] + red[2] + red[3]) * (1.f / DIMC);
    float c = v - mean;
    float s2 = c * c;
#pragma unroll
    for (int off = 32; off; off >>= 1) s2 += __shfl_xor(s2, off);
    __syncthreads();
    if ((t & 63) == 0) red[t >> 6] = s2;
    __syncthreads();
    float var = (red[0] + red[1] + red[2] + red[3]) * (1.f / DIMC);
    out[(size_t)i * DIMC + t] =
        __float2bfloat16(c * rsqrtf(var + 1e-5f) * g[t] + b[t]);
}

// ---------------- fp32 -> bf16 convert (n % 4 == 0) ----------------
__global__ void f2b_kernel(const float* __restrict__ src,
                           __hip_bfloat16* __restrict__ dst, int n)
{
    int i = (blockIdx.x * blockDim.x + threadIdx.x) * 4;
    if (i < n) {
        float4 v = *(const float4*)(src + i);
        dst[i + 0] = __float2bfloat16(v.x);
        dst[i + 1] = __float2bfloat16(v.y);
        dst[i + 2] = __float2bfloat16(v.z);
        dst[i + 3] = __float2bfloat16(v.w);
    }
}

// ---------------- pack wq/wk/wv -> wqkv bf16 [4][384][256], biases [4][384] ----
__global__ __launch_bounds__(256)
void packqkv_kernel(const float* __restrict__ wq, const float* __restrict__ wk,
                    const float* __restrict__ wv, const float* __restrict__ bq,
                    const float* __restrict__ bk, const float* __restrict__ bv,
                    __hip_bfloat16* __restrict__ wqkv, float* __restrict__ bqkv)
{
    int row = blockIdx.x;                 // 0 .. 4*384-1
    int l = row / QKVC, c = row % QKVC;
    int which = c >> 7, cc = c & 127;
    const float* srcw = which == 0 ? wq : which == 1 ? wk : wv;
    const float* srcb = which == 0 ? bq : which == 1 ? bk : bv;
    srcw += ((size_t)l * INNERC + cc) * DIMC;
    wqkv[(size_t)row * DIMC + threadIdx.x] = __float2bfloat16(srcw[threadIdx.x]);
    if (threadIdx.x == 0) bqkv[row] = srcb[l * INNERC + cc];
}

// ---------------- MFMA GEMM v3: 2-phase dbuf, BN=64, 48KB LDS ---------------
// C[M][OUT] = A[M][K] @ W[OUT][K]^T + bias.  BM=128, BK=64, BN=64.
// 256 thr (2x2 waves); wave tile 64x32; acc 4x2 f32x4 = 32 AGPR.
// Stage(t+1) issued BEFORE compute(t); one __syncthreads per K-step (T3 min).
// LDS: A dbuf 2x16KB | W dbuf 2x8KB = 48KB -> 3 blocks/CU.
// Linear grid, A-reuse-major + bijective XCD chunk swizzle (m204).
// EPI: 0 = bias -> bf16; 1 = bias+gelu -> bf16; 2 = bias+res -> fp32.
template<int EPI>
__global__ __launch_bounds__(256)
void mfma_gemm(const __hip_bfloat16* __restrict__ A,
               const __hip_bfloat16* __restrict__ W,
               const float* __restrict__ bias, const float* __restrict__ res,
               void* __restrict__ Cout, int M, int K, int OUT,
               int mtiles, int ntiles)
{
    constexpr int ASZ = 128 * 128;          // one A buf (16KB)
    constexpr int WSZ = 64 * 128;           // one W buf (8KB)
    __shared__ char lds[2 * ASZ + 2 * WSZ];

    int nwg = mtiles * ntiles;
    int orig = blockIdx.x;
    int q = nwg >> 3, r = nwg & 7;
    int xcd = orig & 7, loc = orig >> 3;
    int wgid = (xcd < r ? xcd * (q + 1) : r * (q + 1) + (xcd - r) * q) + loc;
    int bm = (wgid / ntiles) * 128;
    int bn = (wgid % ntiles) * 64;

    int tid = threadIdx.x;
    int lane = tid & 63;
    int w = tid >> 6;
    int wr = w >> 1, wc = w & 1;

    f32x4 acc[4][2] = {};

    auto stage = [&](int t, int b) {
        int k0 = t * 64;
        char* Asb = lds + b * ASZ;
        char* Wsb = lds + 2 * ASZ + b * WSZ;
#pragma unroll
        for (int it = 0; it < 4; ++it) {             // A: 1024 chunks
            int chunk = it * 256 + tid;
            int rr = chunk >> 3;
            int sc = (chunk & 7) ^ (rr & 7);
            int grow = bm + rr;
            if (grow < M)
                gload_lds16((const char*)A + ((size_t)grow * K + k0) * 2 + sc * 16,
                            Asb + chunk * 16);
        }
#pragma unroll
        for (int it = 0; it < 2; ++it) {             // W: 512 chunks
            int chunk = it * 256 + tid;
            int rr = chunk >> 3;
            int sc = (chunk & 7) ^ (rr & 7);
            gload_lds16((const char*)W + ((size_t)(bn + rr) * K + k0) * 2 + sc * 16,
                        Wsb + chunk * 16);
        }
    };

    int nk = K >> 6;
    stage(0, 0);
    __syncthreads();
    for (int t = 0; t < nk; ++t) {
        int cur = t & 1;
        if (t + 1 < nk) stage(t + 1, cur ^ 1);       // prefetch into other buf
        char* As = lds + cur * ASZ;
        char* Ws = lds + 2 * ASZ + cur * WSZ;
#pragma unroll
        for (int s = 0; s < 2; ++s) {
            bf16frag af[4], bfr[2];
            int kb = s * 64 + ((lane >> 4) << 4);
#pragma unroll
            for (int m = 0; m < 4; ++m) {
                int ar = wr * 64 + m * 16 + (lane & 15);
                af[m] = *(const bf16frag*)(As + ar * 128 + (kb ^ ((ar & 7) << 4)));
            }
#pragma unroll
            for (int n = 0; n < 2; ++n) {
                int br = wc * 32 + n * 16 + (lane & 15);
                bfr[n] = *(const bf16frag*)(Ws + br * 128 + (kb ^ ((br & 7) << 4)));
            }
#pragma unroll
            for (int m = 0; m < 4; ++m)
#pragma unroll
                for (int n = 0; n < 2; ++n)
                    acc[m][n] = __builtin_amdgcn_mfma_f32_16x16x32_bf16(
                        af[m], bfr[n], acc[m][n], 0, 0, 0);
        }
        __syncthreads();                 // next buf staged + this buf reads done
    }

#pragma unroll
    for (int m = 0; m < 4; ++m)
#pragma unroll
        for (int rr = 0; rr < 4; ++rr) {
            int grow = bm + wr * 64 + m * 16 + ((lane >> 4) << 2) + rr;
            if (grow < M) {
#pragma unroll
                for (int n = 0; n < 2; ++n) {
                    int gcol = bn + wc * 32 + n * 16 + (lane & 15);
                    float val = acc[m][n][rr] + bias[gcol];
                    if (EPI == 1) val = gelu_exact(val);
                    if (EPI == 2) {
                        val += res[(size_t)grow * OUT + gcol];
                        ((float*)Cout)[(size_t)grow * OUT + gcol] = val;
                    } else {
                        ((__hip_bfloat16*)Cout)[(size_t)grow * OUT + gcol] =
                            __float2bfloat16(val);
                    }
                }
            }
        }
}

// ---------------- CSR build ----------------
__global__ void count_kernel(const int* __restrict__ dst, int* __restrict__ count, int E)
{
    int e = blockIdx.x * blockDim.x + threadIdx.x;
    if (e < E) atomicAdd(&count[dst[e]], 1);
}

__global__ __launch_bounds__(1024)
void scan_kernel(const int* __restrict__ count, int* __restrict__ rowptr, int N)
{
    __shared__ int sdata[1024];
    __shared__ int carry_s;
    int t = threadIdx.x;
    if (t == 0) { carry_s = 0; rowptr[0] = 0; }
    __syncthreads();
    for (int base = 0; base < N; base += 1024) {
        int idx = base + t;
        int v = (idx < N) ? count[idx] : 0;
        sdata[t] = v;
        __syncthreads();
        for (int off = 1; off < 1024; off <<= 1) {
            int add = (t >= off) ? sdata[t - off] : 0;
            __syncthreads();
            sdata[t] += add;
            __syncthreads();
        }
        if (idx < N) rowptr[idx + 1] = carry_s + sdata[t];
        __syncthreads();
        if (t == 0) carry_s += sdata[1023];
        __syncthreads();
    }
}

__global__ void scatter_kernel(const int* __restrict__ src, const int* __restrict__ dst,
                               const int* __restrict__ rowptr, int* __restrict__ cursor,
                               int* __restrict__ srcperm, int E)
{
    int e = blockIdx.x * blockDim.x + threadIdx.x;
    if (e < E) {
        int d = dst[e];
        int pos = rowptr[d] + atomicAdd(&cursor[d], 1);
        srcperm[pos] = src[e];
    }
}

// ---------------- Attention: one WAVE per node, ILP-restructured ------------
__global__ __launch_bounds__(256)
void attn_kernel(const __hip_bfloat16* __restrict__ qkv, const int* __restrict__ rowptr,
                 const int* __restrict__ srcperm, __hip_bfloat16* __restrict__ agg,
                 int N)
{
    int wid = (blockIdx.x * 256 + threadIdx.x) >> 6;   // node index
    if (wid >= N) return;
    int lane = threadIdx.x & 63;
    int h = lane >> 4, u = lane & 15;
    int i = wid;
    int beg = rowptr[i], deg = rowptr[i + 1] - beg;
    const short* base = (const short*)qkv;
    const float scale = 0.17677669529663687f; // 1/sqrt(32)

    bf16frag qf[4];
    const short* qr = base + (size_t)i * QKVC + h * 32;
#pragma unroll
    for (int c = 0; c < 4; ++c) qf[c] = *(const bf16frag*)(qr + c * 8);

    float m_run = -3.4e38f, d_run = 0.f;
    float accx = 0.f, accy = 0.f;

    int j = (u < deg) ? srcperm[beg + u] : i;

    for (int c0 = 0; c0 < deg; c0 += 16) {
        int cn = min(16, deg - c0);
        bool valid = (u < cn);

        const short* kr = base + (size_t)j * QKVC + 128 + h * 32;
        bf16frag kf[4];
#pragma unroll
        for (int c = 0; c < 4; ++c) kf[c] = *(const bf16frag*)(kr + c * 8);

        int nxt = c0 + 16 + u;
        int jn = (nxt < deg) ? srcperm[beg + nxt] : i;

        float dot = 0.f;
#pragma unroll
        for (int c = 0; c < 4; ++c)
#pragma unroll
            for (int e = 0; e < 8; ++e)
                dot += b2f(qf[c][e]) * b2f(kf[c][e]);
        float alpha = valid ? dot * scale : -3.4e38f;

        float cm = alpha;
#pragma unroll
        for (int off = 8; off; off >>= 1) cm = fmaxf(cm, __shfl_xor(cm, off));
        float m_new = fmaxf(m_run, cm);
        float rescale = expf(m_run - m_new);
        float w = valid ? expf(alpha - m_new) : 0.f;
        float dsum = w;
#pragma unroll
        for (int off = 8; off; off >>= 1) dsum += __shfl_xor(dsum, off);
        d_run = d_run * rescale + dsum;
        m_run = m_new;
        accx *= rescale;
        accy *= rescale;

        float wes[16];
        unsigned vws[16];
#pragma unroll
        for (int e = 0; e < 16; ++e) {
            wes[e] = __shfl(w, h * 16 + e);
            int je = __shfl(j, h * 16 + e);        // invalid slots -> row i
            vws[e] = *(const unsigned*)(base + (size_t)je * QKVC + 256 + h * 32 + u * 2);
        }
#pragma unroll
        for (int e = 0; e < 16; ++e) {
            accx += wes[e] * b2f((short)(vws[e] & 0xffff));
            accy += wes[e] * b2f((short)(vws[e] >> 16));
        }
        j = jn;
    }

    float inv = 1.f / (d_run + 1e-16f);
    __hip_bfloat16* outp = agg + (size_t)i * INNERC + h * 32 + u * 2;
    outp[0] = __float2bfloat16(accx * inv);
    outp[1] = __float2bfloat16(accy * inv);
}

// ---------------- Launch ----------------
extern "C" void kernel_launch(void* const* d_in, const int* in_sizes, int n_in,
                              void* d_out, int out_size, void* d_ws, size_t ws_size,
                              hipStream_t stream)
{
    const float* x    = (const float*)d_in[0];
    const int*   ei   = (const int*)  d_in[1];
    const float* ln1g = (const float*)d_in[2];
    const float* ln1b = (const float*)d_in[3];
    const float* wq   = (const float*)d_in[4];
    const float* bq   = (const float*)d_in[5];
    const float* wk   = (const float*)d_in[6];
    const float* bk   = (const float*)d_in[7];
    const float* wv   = (const float*)d_in[8];
    const float* bv   = (const float*)d_in[9];
    const float* wo   = (const float*)d_in[10];
    const float* bo   = (const float*)d_in[11];
    const float* ln2g = (const float*)d_in[12];
    const float* ln2b = (const float*)d_in[13];
    const float* w1   = (const float*)d_in[14];
    const float* b1   = (const float*)d_in[15];
    const float* w2   = (const float*)d_in[16];
    const float* b2   = (const float*)d_in[17];

    const int N = in_sizes[0] / DIMC;   // 20000
    const int E = in_sizes[1] / 2;      // 320000
    const int* srcIdx = ei;
    const int* dstIdx = ei + E;

    char* p = (char*)d_ws;
    auto alloc = [&](size_t bytes) {
        char* r = p;
        p += (bytes + 255) & ~(size_t)255;
        return r;
    };
    float*          xbuf   = (float*)alloc((size_t)N * DIMC * 4);
    __hip_bfloat16* h      = (__hip_bfloat16*)alloc((size_t)N * DIMC * 2);
    __hip_bfloat16* qkv    = (__hip_bfloat16*)alloc((size_t)N * QKVC * 2);
    __hip_bfloat16* agg    = (__hip_bfloat16*)alloc((size_t)N * INNERC * 2);
    __hip_bfloat16* u      = (__hip_bfloat16*)alloc((size_t)N * 1024 * 2);
    int*            rowptr = (int*)alloc((size_t)(N + 1) * 4);
    int*            cnt    = (int*)alloc((size_t)N * 4);
    int*            srcperm= (int*)alloc((size_t)E * 4);
    __hip_bfloat16* wqkvB  = (__hip_bfloat16*)alloc((size_t)4 * QKVC * DIMC * 2);
    float*          bqkvF  = (float*)alloc((size_t)4 * QKVC * 4);
    __hip_bfloat16* woB    = (__hip_bfloat16*)alloc((size_t)4 * DIMC * INNERC * 2);
    __hip_bfloat16* w1B    = (__hip_bfloat16*)alloc((size_t)4 * 1024 * DIMC * 2);
    __hip_bfloat16* w2B    = (__hip_bfloat16*)alloc((size_t)4 * DIMC * 1024 * 2);

    // Weight conversion (per-call, deterministic)
    packqkv_kernel<<<4 * QKVC, 256, 0, stream>>>(wq, wk, wv, bq, bk, bv, wqkvB, bqkvF);
    {
        int n = 4 * DIMC * INNERC;
        f2b_kernel<<<(n / 4 + 255) / 256, 256, 0, stream>>>(wo, woB, n);
        n = 4 * 1024 * DIMC;
        f2b_kernel<<<(n / 4 + 255) / 256, 256, 0, stream>>>(w1, w1B, n);
        f2b_kernel<<<(n / 4 + 255) / 256, 256, 0, stream>>>(w2, w2B, n);
    }

    // CSR build
    hipMemsetAsync(cnt, 0, (size_t)N * 4, stream);
    count_kernel<<<(E + 255) / 256, 256, 0, stream>>>(dstIdx, cnt, E);
    scan_kernel<<<1, 1024, 0, stream>>>(cnt, rowptr, N);
    hipMemsetAsync(cnt, 0, (size_t)N * 4, stream);
    scatter_kernel<<<(E + 255) / 256, 256, 0, stream>>>(srcIdx, dstIdx, rowptr, cnt, srcperm, E);

    int mt = (N + 127) / 128;        // 157
    int attnBlocks = (N * 64 + 255) / 256;
    for (int l = 0; l < 4; ++l) {
        const float* xin = (l == 0) ? x : xbuf;
        ln_kernel<<<N, 256, 0, stream>>>(xin, ln1g + l * DIMC, ln1b + l * DIMC, h);
        // QKV: OUT=384 -> 6 ntiles, 942 blocks
        mfma_gemm<0><<<mt * 6, 256, 0, stream>>>(
            h, wqkvB + (size_t)l * QKVC * DIMC, bqkvF + l * QKVC, nullptr,
            qkv, N, DIMC, QKVC, mt, 6);
        attn_kernel<<<attnBlocks, 256, 0, stream>>>(qkv, rowptr, srcperm, agg, N);
        // out-proj: OUT=256, K=128 -> 628 blocks
        mfma_gemm<2><<<mt * 4, 256, 0, stream>>>(
            agg, woB + (size_t)l * DIMC * INNERC, bo + l * DIMC, xin,
            xbuf, N, INNERC, DIMC, mt, 4);
        ln_kernel<<<N, 256, 0, stream>>>(xbuf, ln2g + l * DIMC, ln2b + l * DIMC, h);
        // FF1: OUT=1024 -> 16 ntiles, 2512 blocks
        mfma_gemm<1><<<mt * 16, 256, 0, stream>>>(
            h, w1B + (size_t)l * 1024 * DIMC, b1 + l * 1024, nullptr,
            u, N, DIMC, 1024, mt, 16);
        float* xout = (l == 3) ? (float*)d_out : xbuf;
        // FF2: OUT=256, K=1024 -> 628 blocks
        mfma_gemm<2><<<mt * 4, 256, 0, stream>>>(
            u, w2B + (size_t)l * DIMC * 1024, b2 + l * DIMC, xbuf,
            xout, N, 1024, DIMC, mt, 4);
    }
}